// Round 21
// baseline (223.308 us; speedup 1.0000x reference)
//
#include <hip/hip_runtime.h>
#include <hip/hip_bf16.h>
#include <math.h>

// Problem constants (B=32, T=256, V=32000, D=512)
#define R   8192    // B*T rows
#define TT  256
#define D   512
#define V   32000
#define G3  1536    // 3*D (z|f|o)

typedef __attribute__((ext_vector_type(2))) float f32x2;
typedef __attribute__((ext_vector_type(4))) float f32x4;
typedef __attribute__((ext_vector_type(4))) int   i32x4;
typedef __attribute__((ext_vector_type(8))) int   i32x8;

__device__ __forceinline__ float bf2f(ushort u) {
  union { unsigned int i; float f; } x; x.i = ((unsigned int)u) << 16; return x.f;
}
__device__ __forceinline__ ushort f2bf(float f) {   // RNE
  union { float f; unsigned int i; } x; x.f = f;
  unsigned int r = x.i + 0x7fffu + ((x.i >> 16) & 1u);
  return (ushort)(r >> 16);
}

// raw hardware exp2: exactly the terminal op of __expf, no libm guards
__device__ __forceinline__ float hw_exp2(float x) {
  float r;
  asm("v_exp_f32 %0, %1" : "=v"(r) : "v"(x));
  return r;
}

// packed fp32 VOP3P ops: 2 f32 per instruction (CDNA2+)
__device__ __forceinline__ f32x2 pk_fma(f32x2 a, f32x2 b, f32x2 c) {
  f32x2 d;
  asm("v_pk_fma_f32 %0, %1, %2, %3" : "=v"(d) : "v"(a), "v"(b), "v"(c));
  return d;
}
__device__ __forceinline__ f32x2 pk_add(f32x2 a, f32x2 b) {
  f32x2 d;
  asm("v_pk_add_f32 %0, %1, %2" : "=v"(d) : "v"(a), "v"(b));
  return d;
}

// f32 (pre-scaled) -> fp4 e2m1 code, RNE to grid {0,.5,1,1.5,2,3,4,6}, clamp 6.
__device__ __forceinline__ unsigned char f2e2m1(float v) {
  unsigned char s = (v < 0.f) ? 8 : 0;
  float a = fabsf(v);
  unsigned char q;
  if      (a < 0.25f) q = 0;
  else if (a < 0.75f) q = 1;
  else if (a < 1.25f) q = 2;
  else if (a < 1.75f) q = 3;
  else if (a < 2.5f)  q = 4;
  else if (a < 3.5f)  q = 5;
  else if (a < 5.0f)  q = 6;
  else                q = 7;
  return s | q;
}

// e2m1 nibble -> f32 (arithmetic, no LUT)
__device__ __forceinline__ float e2m1f(int n) {
  int e = (n >> 1) & 3, m = n & 1;
  float v;
  if (e == 0) v = 0.5f * (float)m;
  else { union { unsigned u; float f; } x;
         x.u = ((unsigned)(e + 126) << 23) | ((unsigned)m << 22); v = x.f; }
  return (n & 8) ? -v : v;
}

// within-128-block nibble offset of the phys-K map
__device__ __forceinline__ int physwb(int k) {
  return (((k >> 3) & 3) << 5) | (((k >> 5) & 3) << 3) | (k & 7);
}
// pair-byte offset for even d
__device__ __forceinline__ int pairbyte(int d) {
  return (((d & ~127) + physwb(d & 127)) >> 1);
}

__device__ __forceinline__ void gload16(const void* g, void* l) {
  __builtin_amdgcn_global_load_lds((const __attribute__((address_space(1))) void*)g,
                                   (__attribute__((address_space(3))) void*)l, 16, 0, 0);
}

// ---------------- embedding gather -> XA4 fp4 phys-K [R][1024 elems]=[512B], x*16 ----------------
__global__ __launch_bounds__(256) void embed_kernel(const int* __restrict__ tok,
                                                    const float4* __restrict__ emb,
                                                    unsigned char* __restrict__ XA4) {
  int idx = blockIdx.x * 256 + threadIdx.x;   // over R*128 float4s
  int r = idx >> 7, d4 = idx & 127;
  float4 v = emb[(size_t)tok[r] * 128 + d4];
  int d = d4 * 4;
  unsigned char n0 = f2e2m1(v.x * 16.f), n1 = f2e2m1(v.y * 16.f);
  unsigned char n2 = f2e2m1(v.z * 16.f), n3 = f2e2m1(v.w * 16.f);
  uchar2 b2; b2.x = n0 | (n1 << 4); b2.y = n2 | (n3 << 4);
  int bx2 = pairbyte(d);
  *(uchar2*)(XA4 + (size_t)r * 512 + 256 + bx2) = b2;            // x part
  int t = r & (TT - 1);
  if (t < TT - 1) *(uchar2*)(XA4 + (size_t)(r + 1) * 512 + bx2) = b2;  // next row x_prev
  if (t == 0) { uchar2 z = {0, 0}; *(uchar2*)(XA4 + (size_t)r * 512 + bx2) = z; }
}

// ---------------- fp4 phys-K transpose-convert: 16 elems -> 8 bytes ----------------
__device__ __forceinline__ void tconv4_write(const float (*tile)[65],
                                             unsigned char* __restrict__ dstrow0,
                                             size_t ldb4, int k0, int t, float scale) {
  int nn = t & 63, h = t >> 6;
  union { unsigned char c[8]; uint2 q; } u;
#pragma unroll
  for (int ksl = 0; ksl < 2; ++ksl)
#pragma unroll
    for (int jp = 0; jp < 4; ++jp) {
      unsigned char l4 = f2e2m1(tile[ksl * 32 + h * 8 + jp * 2    ][nn] * scale);
      unsigned char h4 = f2e2m1(tile[ksl * 32 + h * 8 + jp * 2 + 1][nn] * scale);
      u.c[ksl * 4 + jp] = l4 | (h4 << 4);
    }
  unsigned char* dst = dstrow0 + (size_t)nn * ldb4 + ((k0 & ~127) >> 1) + h * 16 + ((k0 & 64) ? 8 : 0);
  *(uint2*)dst = u.q;
}

// ---------------- weight transpose+convert (BOTH layers): WT4[1536][512B] fp4 phys-K, W*16 ----------------
__global__ __launch_bounds__(256) void wconv(const float* __restrict__ Wz0,
                                             const float* __restrict__ Wf0,
                                             const float* __restrict__ Wo0,
                                             const float* __restrict__ Wz1,
                                             const float* __restrict__ Wf1,
                                             const float* __restrict__ Wo1,
                                             unsigned char* __restrict__ WT40,
                                             unsigned char* __restrict__ WT41) {
  __shared__ float tile[64][65];
  int z = blockIdx.z;
  int layer = z >= 6 ? 1 : 0, zz = z - 6 * layer;
  int g = zz >> 1, i = zz & 1;
  const float* src = layer == 0 ? (g == 0 ? Wz0 : (g == 1 ? Wf0 : Wo0))
                                : (g == 0 ? Wz1 : (g == 1 ? Wf1 : Wo1));
  unsigned char* WT4 = layer == 0 ? WT40 : WT41;
  src += (size_t)i * D * D;
  int d0 = blockIdx.x * 64, e0 = blockIdx.y * 64;
  int t = threadIdx.x, c = t & 63, rq = t >> 6;
#pragma unroll
  for (int p = 0; p < 16; ++p) {
    int dd = p * 4 + rq;
    tile[dd][c] = src[(size_t)(d0 + dd) * D + e0 + c];   // [k=d][n=e]
  }
  __syncthreads();
  tconv4_write(tile, WT4 + (size_t)(g * D + e0) * 512, 512, i * 512 + d0, t, 16.f);
}

// ---------------- softmax weight transpose+convert: fp4 x32 ----------------
__global__ __launch_bounds__(256) void swconv(const float* __restrict__ SW,
                                              unsigned char* __restrict__ SW4T) {
  __shared__ float tile[64][65];
  int k0 = blockIdx.x * 64, n0 = blockIdx.y * 64;
  int t = threadIdx.x, c = t & 63, rq = t >> 6;
#pragma unroll
  for (int p = 0; p < 16; ++p) {
    int kk = p * 4 + rq;
    tile[kk][c] = SW[(size_t)(k0 + kk) * V + n0 + c];
  }
  __syncthreads();
  tconv4_write(tile, SW4T + (size_t)n0 * 256, 256, k0, t, 32.f);   // W x 2^5
}

// ---------------- MX-fp4 128x128 GEMM core (r20 verified; for gemm_pre) ----------------
template<int LD4, int NKT, int WSC, int ASC>
__device__ __forceinline__ void mx4_core128(const unsigned char* __restrict__ A4,
                                            const unsigned char* __restrict__ B4,
                                            int row0, int col0, char* lds,
                                            f32x4 acc[4][4]) {
  char* As = lds;            // 128 rows x 64B
  char* Bs = lds + 8192;     // 128 rows x 64B
  const int t = threadIdx.x, lane = t & 63, w = t >> 6;
  const int wm = w >> 1, wn = w & 1;
  const int lo = lane & 15, hi = lane >> 4;
  const int gr = t >> 2;                                       // row within 64-row issue
  const int ls = ((t & 3) - ((gr & 3) + ((gr >> 2) & 3))) & 3; // inverse-swz source slot

#pragma unroll 1
  for (int kt = 0; kt < NKT; ++kt) {
    const int k0b = kt * 64;
#pragma unroll
    for (int i = 0; i < 2; ++i) {
      gload16(A4 + (size_t)(row0 + i * 64 + gr) * LD4 + k0b + ls * 16,
              As + i * 4096 + t * 16);
      gload16(B4 + (size_t)(col0 + i * 64 + gr) * LD4 + k0b + ls * 16,
              Bs + i * 4096 + t * 16);
    }
    __syncthreads();
    i32x8 b4[4];
#pragma unroll
    for (int ni = 0; ni < 4; ++ni) {
      int r = wn * 64 + ni * 16 + lo;
      int ps = (hi + (r & 3) + ((r >> 2) & 3)) & 3;
      union { i32x8 v8; i32x4 v4[2]; } u;
      u.v4[0] = *(const i32x4*)(Bs + r * 64 + ps * 16);
      i32x4 z4 = {0, 0, 0, 0};
      u.v4[1] = z4;
      b4[ni] = u.v8;
    }
#pragma unroll
    for (int mi = 0; mi < 4; ++mi) {
      int r = wm * 64 + mi * 16 + lo;
      int ps = (hi + (r & 3) + ((r >> 2) & 3)) & 3;
      union { i32x8 v8; i32x4 v4[2]; } u;
      u.v4[0] = *(const i32x4*)(As + r * 64 + ps * 16);
      i32x4 z4 = {0, 0, 0, 0};
      u.v4[1] = z4;
      i32x8 a4 = u.v8;
#pragma unroll
      for (int ni = 0; ni < 4; ++ni)
        acc[mi][ni] = __builtin_amdgcn_mfma_scale_f32_16x16x128_f8f6f4(
            b4[ni], a4, acc[mi][ni], 4, 4, 0, WSC, 0, ASC);
    }
    __syncthreads();
  }
}

// ---------------- QRNN pre-activation GEMM (8192x1536x1024, MX-fp4, 128x128, fused bias) ----------------
template<int ASC>
__global__ __launch_bounds__(256, 2) void gemm_pre_fp4(const unsigned char* __restrict__ A4,
                                                       const unsigned char* __restrict__ B4,
                                                       const float* __restrict__ bz,
                                                       const float* __restrict__ bf,
                                                       const float* __restrict__ bo,
                                                       ushort* __restrict__ PRE) {
  __shared__ char lds[16384];
  const int t = threadIdx.x, lane = t & 63, w = t >> 6;
  const int wm = w >> 1, wn = w & 1;
  const int lo = lane & 15, hi = lane >> 4;
  const int row0 = blockIdx.x * 128, col0 = blockIdx.y * 128;
  const int g = col0 >> 9;                       // gate uniform per block
  const float* bg = (g == 0) ? bz : (g == 1 ? bf : bo);

  f32x4 acc[4][4];
#pragma unroll
  for (int i = 0; i < 4; ++i)
#pragma unroll
    for (int j = 0; j < 4; ++j) { f32x4 z = {0.f,0.f,0.f,0.f}; acc[i][j] = z; }

  mx4_core128<512, 8, 123, ASC>(A4, B4, row0, col0, lds, acc);

#pragma unroll
  for (int mi = 0; mi < 4; ++mi) {
    const int row = row0 + wm * 64 + mi * 16 + lo;
#pragma unroll
    for (int ni = 0; ni < 4; ++ni) {
      const int colb = col0 + wn * 64 + ni * 16 + hi * 4;
      const int eb = colb & 511;
      ushort4 v;
      v.x = f2bf(acc[mi][ni][0] + bg[eb + 0]);
      v.y = f2bf(acc[mi][ni][1] + bg[eb + 1]);
      v.z = f2bf(acc[mi][ni][2] + bg[eb + 2]);
      v.w = f2bf(acc[mi][ni][3] + bg[eb + 3]);
      *(ushort4*)(PRE + (size_t)row * G3 + colb) = v;
    }
  }
}

// ---------------- target-logit kernel (+ SUM zero): fp4 path ----------------
__global__ __launch_bounds__(256) void tgl_kernel(const unsigned char* __restrict__ H4,
                                                  const unsigned char* __restrict__ SW4T,
                                                  const float* __restrict__ SB,
                                                  const int* __restrict__ tgt,
                                                  float* __restrict__ TGL,
                                                  float* __restrict__ SUM) {
  int wid  = (blockIdx.x * 256 + threadIdx.x) >> 6;   // one wave per row
  int lane = threadIdx.x & 63;
  if (lane == 0) SUM[wid] = 0.f;                      // zero before lse's atomics
  int tg = tgt[wid];
  unsigned int hv = *(const unsigned int*)(H4   + (size_t)wid * 256 + lane * 4);
  unsigned int wv = *(const unsigned int*)(SW4T + (size_t)tg  * 256 + lane * 4);
  float s = 0.f;
#pragma unroll
  for (int k = 0; k < 8; ++k)
    s += e2m1f((hv >> (4 * k)) & 15) * e2m1f((wv >> (4 * k)) & 15);
#pragma unroll
  for (int m = 1; m < 64; m <<= 1) s += __shfl_xor(s, m, 64);
  if (lane == 0) TGL[wid] = s * (1.f / 128.f) + SB[tg];
}

// ---------------- shared MX-fp4 256x128 GEMM core (VERIFIED r16-r20; for lse) ----------------
template<int LD4, int NKT, int WSC, int ASC>
__device__ __forceinline__ void mx4_core(const unsigned char* __restrict__ A4,
                                         const unsigned char* __restrict__ B4,
                                         int row0, int col0, char* lds,
                                         f32x4 acc[8][4]) {
  char* As = lds;            // 256 rows x 64B
  char* Bs = lds + 16384;    // 128 rows x 64B
  const int t = threadIdx.x, lane = t & 63, w = t >> 6;
  const int wm = w >> 1, wn = w & 1;
  const int lo = lane & 15, hi = lane >> 4;
  const int gr = t >> 2;                                       // row within issue
  const int ls = ((t & 3) - ((gr & 3) + ((gr >> 2) & 3))) & 3; // inverse-swz source slot

#pragma unroll 1
  for (int kt = 0; kt < NKT; ++kt) {
    const int k0b = kt * 64;
#pragma unroll
    for (int i = 0; i < 4; ++i)
      gload16(A4 + (size_t)(row0 + i * 64 + gr) * LD4 + k0b + ls * 16,
              As + i * 4096 + t * 16);
#pragma unroll
    for (int i = 0; i < 2; ++i)
      gload16(B4 + (size_t)(col0 + i * 64 + gr) * LD4 + k0b + ls * 16,
              Bs + i * 4096 + t * 16);
    __syncthreads();
    i32x8 b4[4];
#pragma unroll
    for (int ni = 0; ni < 4; ++ni) {
      int r = wn * 64 + ni * 16 + lo;
      int ps = (hi + (r & 3) + ((r >> 2) & 3)) & 3;
      union { i32x8 v8; i32x4 v4[2]; } u;
      u.v4[0] = *(const i32x4*)(Bs + r * 64 + ps * 16);
      i32x4 z4 = {0, 0, 0, 0};
      u.v4[1] = z4;
      b4[ni] = u.v8;
    }
#pragma unroll
    for (int mi = 0; mi < 8; ++mi) {
      int r = wm * 128 + mi * 16 + lo;
      int ps = (hi + (r & 3) + ((r >> 2) & 3)) & 3;
      union { i32x8 v8; i32x4 v4[2]; } u;
      u.v4[0] = *(const i32x4*)(As + r * 64 + ps * 16);
      i32x4 z4 = {0, 0, 0, 0};
      u.v4[1] = z4;
      i32x8 a4 = u.v8;
#pragma unroll
      for (int ni = 0; ni < 4; ++ni)
        acc[mi][ni] = __builtin_amdgcn_mfma_scale_f32_16x16x128_f8f6f4(
            b4[ni], a4, acc[mi][ni], 4, 4, 0, WSC, 0, ASC);
    }
    __syncthreads();
  }
}

// ---------------- MX-fp4 logits GEMM + fused exp-sum (PACKED-fp32 epilogue) ----------------
// Epilogue per 2 logits: 1 v_pk_fma_f32 + 2 v_exp_f32 + 1 v_pk_add_f32
// (was 2 fma + 2 exp + 2 add). Math bit-identical per lane.
__global__ __launch_bounds__(256, 2) void gemm_lse_fp4(const unsigned char* __restrict__ A4,
                                                       const unsigned char* __restrict__ B4,
                                                       const float* __restrict__ SB,
                                                       float* __restrict__ SUM) {
  __shared__ char lds[24576];
  const int t = threadIdx.x, lane = t & 63, w = t >> 6;
  const int wm = w >> 1, wn = w & 1;
  const int lo = lane & 15, hi = lane >> 4;
  const int row0 = blockIdx.x * 256, col0 = blockIdx.y * 128;
  const float L2E = 1.442695041f;
  const f32x2 l2e2 = {L2E, L2E};

  f32x2 sb2[8];   // SB * log2(e) pairs, pre-folded
#pragma unroll
  for (int ni = 0; ni < 4; ++ni)
#pragma unroll
    for (int jp = 0; jp < 2; ++jp) {
      int cb = col0 + wn * 64 + ni * 16 + hi * 4 + jp * 2;
      f32x2 v = {SB[cb] * L2E, SB[cb + 1] * L2E};
      sb2[ni * 2 + jp] = v;
    }

  f32x4 acc[8][4];
#pragma unroll
  for (int i = 0; i < 8; ++i)
#pragma unroll
    for (int j = 0; j < 4; ++j) { f32x4 z = {0.f,0.f,0.f,0.f}; acc[i][j] = z; }

  mx4_core<256, 4, 122, 125>(A4, B4, row0, col0, lds, acc);  // W x2^-5, H x2^-2

#pragma unroll
  for (int mi = 0; mi < 8; ++mi) {
    const int row = row0 + wm * 128 + mi * 16 + lo;
    f32x2 s01 = {0.f, 0.f}, s23 = {0.f, 0.f};
#pragma unroll
    for (int ni = 0; ni < 4; ++ni) {
      f32x2 a01 = {acc[mi][ni][0], acc[mi][ni][1]};
      f32x2 a23 = {acc[mi][ni][2], acc[mi][ni][3]};
      f32x2 t01 = pk_fma(a01, l2e2, sb2[ni * 2 + 0]);
      f32x2 t23 = pk_fma(a23, l2e2, sb2[ni * 2 + 1]);
      f32x2 e01, e23;
      e01.x = hw_exp2(t01.x); e01.y = hw_exp2(t01.y);
      e23.x = hw_exp2(t23.x); e23.y = hw_exp2(t23.y);
      s01 = pk_add(s01, e01);
      s23 = pk_add(s23, e23);
    }
    float s = (s01.x + s01.y) + (s23.x + s23.y);
    s += __shfl_xor(s, 16, 64);
    s += __shfl_xor(s, 32, 64);
    if (hi == 0) atomicAdd(&SUM[row], s);
  }
}

// ---------------- fused 8-segment parallel fo-pool scan (r20 exact) ----------------
__global__ __launch_bounds__(512) void scan_fused(const ushort* __restrict__ PRE,
                                                  unsigned char* __restrict__ OUT4,
                                                  int mode) {
  __shared__ float Als[8][64], Bls[8][64];
  const int b = blockIdx.x, dc = blockIdx.y;
  const int tid = threadIdx.x, dl = tid & 63, s = tid >> 6;   // s in 0..7, wave-uniform
  const int d = dc * 64 + dl;
  const ushort* p  = PRE + (size_t)b * TT * G3 + d;
  const ushort* ps = p + (size_t)(s * 32) * G3;

  float zs[32], fs[32];
  float a = 1.f, c = 0.f;
#pragma unroll
  for (int t0 = 0; t0 < 32; t0 += 8) {
    float pz[8], pf[8];
#pragma unroll
    for (int i = 0; i < 8; ++i) {
      const ushort* q = ps + (size_t)(t0 + i) * G3;
      pz[i] = bf2f(q[0]); pf[i] = bf2f(q[512]);
    }
#pragma unroll
    for (int i = 0; i < 8; ++i) {
      float z = 2.f / (1.f + __expf(-2.f * pz[i])) - 1.f;
      float f = 1.f / (1.f + __expf(-pf[i]));
      zs[t0 + i] = z; fs[t0 + i] = f;
      c = f * c + (1.f - f) * z;
      a *= f;
    }
  }
  Als[s][dl] = a; Bls[s][dl] = c;
  __syncthreads();
  float cc = 0.f;
  for (int u = 0; u < s; ++u)          // wave-uniform bound, no divergence
    cc = Als[u][dl] * cc + Bls[u][dl];

  const int bx2 = pairbyte(d);
#pragma unroll
  for (int t0 = 0; t0 < 32; t0 += 8) {
    float po[8];
#pragma unroll
    for (int i = 0; i < 8; ++i)
      po[i] = bf2f(ps[(size_t)(t0 + i) * G3 + 1024]);
#pragma unroll
    for (int i = 0; i < 8; ++i) {
      float o = 1.f / (1.f + __expf(-po[i]));
      float f = fs[t0 + i];
      cc = f * cc + (1.f - f) * zs[t0 + i];
      float h = o * cc;
      int tt = s * 32 + t0 + i;
      size_t r = (size_t)b * TT + tt;
      unsigned char nib = f2e2m1(h * 4.f);
      unsigned int pn = __shfl_xor((unsigned int)nib, 1, 64);  // partner (d^1) nibble
      if ((dl & 1) == 0) {
        unsigned char byte = nib | ((unsigned char)pn << 4);
        if (mode == 0) {
          OUT4[r * 512 + 256 + bx2] = byte;                    // x part
          if (tt < TT - 1) OUT4[(r + 1) * 512 + bx2] = byte;   // x_prev of next row
          if (tt == 0)     OUT4[r * 512 + bx2] = 0;
        } else {
          OUT4[r * 256 + bx2] = byte;
        }
      }
    }
  }
}

// ---------------- final cost ----------------
__global__ __launch_bounds__(256) void cost_kernel(const float* __restrict__ sumexp,
                                                   const float* __restrict__ tgl,
                                                   float* __restrict__ out) {
  int t = threadIdx.x;
  float s = 0.f;
  for (int r = t; r < R; r += 256) s += logf(sumexp[r]) - tgl[r];
#pragma unroll
  for (int m = 1; m < 64; m <<= 1) s += __shfl_xor(s, m, 64);
  __shared__ float red[4];
  int wave = t >> 6, lane = t & 63;
  if (lane == 0) red[wave] = s;
  __syncthreads();
  if (t == 0) out[0] = (red[0] + red[1] + red[2] + red[3]) / (float)R;
}

extern "C" void kernel_launch(void* const* d_in, const int* in_sizes, int n_in,
                              void* d_out, int out_size, void* d_ws, size_t ws_size,
                              hipStream_t stream) {
  const int*   tok = (const int*)d_in[0];
  const int*   tgt = (const int*)d_in[1];
  const float* emb = (const float*)d_in[2];
  const float* Wz0 = (const float*)d_in[3];  const float* bz0 = (const float*)d_in[4];
  const float* Wf0 = (const float*)d_in[5];  const float* bf0 = (const float*)d_in[6];
  const float* Wo0 = (const float*)d_in[7];  const float* bo0 = (const float*)d_in[8];
  const float* Wz1 = (const float*)d_in[9];  const float* bz1 = (const float*)d_in[10];
  const float* Wf1 = (const float*)d_in[11]; const float* bf1 = (const float*)d_in[12];
  const float* Wo1 = (const float*)d_in[13]; const float* bo1 = (const float*)d_in[14];
  const float* SW  = (const float*)d_in[15]; const float* SB  = (const float*)d_in[16];
  float* out = (float*)d_out;

  // workspace layout (bytes), max ~49.7 MB:
  char* base = (char*)d_ws;
  unsigned char* XA4  = (unsigned char*)(base);             //  4,194,304 [R][512B] fp4
  unsigned char* YA4  = (unsigned char*)(base + 4194304);   //  4,194,304
  ushort*        PRE  = (ushort*)(base + 8388608);          // 25,165,824 [R][1536] bf16
  unsigned char* WT40 = (unsigned char*)(base + 37748736);  //    786,432 [1536][512B] fp4
  unsigned char* WT41 = (unsigned char*)(base + 38535168);  //    786,432
  float*         SUM  = (float*)(base + 39321600);          //     32,768
  float*         TGL  = (float*)(base + 39354368);          //     32,768
  unsigned char* H4   = (unsigned char*)(base + 39387136);  //  2,097,152 [R][256B] fp4
  unsigned char* SW4T = (unsigned char*)(base + 41484288);  //  8,192,000 [V][256B] fp4

  embed_kernel<<<R * 128 / 256, 256, 0, stream>>>(tok, (const float4*)emb, XA4);
  wconv<<<dim3(8, 8, 12), 256, 0, stream>>>(Wz0, Wf0, Wo0, Wz1, Wf1, Wo1, WT40, WT41);

  gemm_pre_fp4<123><<<dim3(64, 12), 256, 0, stream>>>(XA4, WT40, bz0, bf0, bo0, PRE);  // A=x*16
  scan_fused<<<dim3(32, 8), 512, 0, stream>>>(PRE, YA4, 0);
  gemm_pre_fp4<125><<<dim3(64, 12), 256, 0, stream>>>(YA4, WT41, bz1, bf1, bo1, PRE);  // A=h*4
  scan_fused<<<dim3(32, 8), 512, 0, stream>>>(PRE, H4, 1);

  swconv<<<dim3(8, 500), 256, 0, stream>>>(SW, SW4T);
  tgl_kernel<<<R / 4, 256, 0, stream>>>(H4, SW4T, SB, tgt, TGL, SUM);
  gemm_lse_fp4<<<dim3(32, 250), 256, 0, stream>>>(H4, SW4T, SB, SUM);
  cost_kernel<<<1, 256, 0, stream>>>(SUM, TGL, out);
}